// Round 1
// baseline (556.759 us; speedup 1.0000x reference)
//
#include <hip/hip_runtime.h>

static constexpr int N_NODES = 50000;
static constexpr int N_EDGES = 800000;
static constexpr int IN_C  = 64;
static constexpr int HID_C = 64;
static constexpr int OUT_C = 32;

// ---------------------------------------------------------------------------
// Scatter-add: one wave (64 lanes) per edge; lane = channel.
// feat row gather is one coalesced 256B load per edge; scatter is 64 f32
// device-scope atomics into the (L2-resident) 12.8MB accumulator.
// ---------------------------------------------------------------------------
__global__ __launch_bounds__(256) void k_scatter64(
    const float* __restrict__ feat,
    const int*   __restrict__ srcv,
    const int*   __restrict__ dstv,
    float*       __restrict__ agg)
{
    int t    = blockIdx.x * blockDim.x + threadIdx.x;
    int e    = t >> 6;
    int lane = t & 63;
    if (e >= N_EDGES) return;
    int s = srcv[e];          // same addr across wave -> broadcast load
    int d = dstv[e];
    float v = feat[(size_t)s * 64 + lane];
    atomicAdd(agg + (size_t)d * 64 + lane, v);
}

// ---------------------------------------------------------------------------
// h = relu(agg @ W_rel + x @ W_root + b)   [N,64]x[64,64]
// One wave per row. Weights live in registers (64+64 VGPR), row values are
// broadcast with __shfl(v, k) (constant k -> v_readlane + SGPR-operand FMA).
// ---------------------------------------------------------------------------
__global__ __launch_bounds__(256) void k_lin1_relu(
    const float* __restrict__ x,
    const float* __restrict__ agg,
    const float* __restrict__ Wroot,   // [64][64]
    const float* __restrict__ Wrel,    // [64][64]
    const float* __restrict__ bias,    // [64]
    float*       __restrict__ h)
{
    int lane = threadIdx.x & 63;
    float wr[64], wl[64];
#pragma unroll
    for (int k = 0; k < 64; ++k) {
        wr[k] = Wroot[k * 64 + lane];
        wl[k] = Wrel [k * 64 + lane];
    }
    float bv = bias[lane];

    int wid    = (blockIdx.x * blockDim.x + threadIdx.x) >> 6;
    int nwaves = (gridDim.x * blockDim.x) >> 6;
    for (int row = wid; row < N_NODES; row += nwaves) {
        float xv = x  [(size_t)row * 64 + lane];
        float av = agg[(size_t)row * 64 + lane];
        float sum = bv;
#pragma unroll
        for (int k = 0; k < 64; ++k) {
            float xk = __shfl(xv, k);
            float ak = __shfl(av, k);
            sum += xk * wr[k] + ak * wl[k];
        }
        h[(size_t)row * 64 + lane] = fmaxf(sum, 0.0f);
    }
}

// ---------------------------------------------------------------------------
// out = agg2 @ W_rel2 + h @ W_root2 + b2   [N,64]x[64,32]
// One wave per row; all 64 lanes hold the row, lanes 0..31 produce channels.
// ---------------------------------------------------------------------------
__global__ __launch_bounds__(256) void k_lin2(
    const float* __restrict__ h,
    const float* __restrict__ agg,
    const float* __restrict__ Wroot,   // [64][32]
    const float* __restrict__ Wrel,    // [64][32]
    const float* __restrict__ bias,    // [32]
    float*       __restrict__ out)
{
    int lane = threadIdx.x & 63;
    int c    = lane & 31;
    float wr[64], wl[64];
#pragma unroll
    for (int k = 0; k < 64; ++k) {
        wr[k] = Wroot[k * 32 + c];
        wl[k] = Wrel [k * 32 + c];
    }
    float bv = bias[c];

    int wid    = (blockIdx.x * blockDim.x + threadIdx.x) >> 6;
    int nwaves = (gridDim.x * blockDim.x) >> 6;
    for (int row = wid; row < N_NODES; row += nwaves) {
        float hv = h  [(size_t)row * 64 + lane];   // full 64-ch row across wave
        float av = agg[(size_t)row * 64 + lane];
        float sum = bv;
#pragma unroll
        for (int k = 0; k < 64; ++k) {
            float hk = __shfl(hv, k);
            float ak = __shfl(av, k);
            sum += hk * wr[k] + ak * wl[k];
        }
        if (lane < 32) out[(size_t)row * 32 + c] = sum;
    }
}

extern "C" void kernel_launch(void* const* d_in, const int* in_sizes, int n_in,
                              void* d_out, int out_size, void* d_ws, size_t ws_size,
                              hipStream_t stream) {
    const float* x      = (const float*)d_in[0];
    const int*   ei     = (const int*)  d_in[1];   // [2][800000], int32
    const float* Wrel1  = (const float*)d_in[2];
    const float* Wroot1 = (const float*)d_in[3];
    const float* b1     = (const float*)d_in[4];
    const float* Wrel2  = (const float*)d_in[5];
    const float* Wroot2 = (const float*)d_in[6];
    const float* b2     = (const float*)d_in[7];
    float*       out    = (float*)d_out;

    const int* srcv = ei;
    const int* dstv = ei + N_EDGES;

    // Workspace layout (25.6 MB): agg (reused by both layers) | h
    float* agg = (float*)d_ws;
    float* h   = agg + (size_t)N_NODES * 64;
    size_t aggBytes = (size_t)N_NODES * 64 * sizeof(float);

    const int scatterBlocks = (int)(((long long)N_EDGES * 64 + 255) / 256);

    // Layer 1
    hipMemsetAsync(agg, 0, aggBytes, stream);
    k_scatter64<<<scatterBlocks, 256, 0, stream>>>(x, srcv, dstv, agg);
    k_lin1_relu<<<2048, 256, 0, stream>>>(x, agg, Wroot1, Wrel1, b1, h);

    // Layer 2 (reuse agg buffer)
    hipMemsetAsync(agg, 0, aggBytes, stream);
    k_scatter64<<<scatterBlocks, 256, 0, stream>>>(h, srcv, dstv, agg);
    k_lin2<<<2048, 256, 0, stream>>>(h, agg, Wroot2, Wrel2, b2, out);
}

// Round 2
// 274.129 us; speedup vs baseline: 2.0310x; 2.0310x over previous
//
#include <hip/hip_runtime.h>

static constexpr int N_NODES = 50000;
static constexpr int N_EDGES = 800000;

static constexpr int SCAN_CHUNK = 1024;                       // elems per block
static constexpr int SCAN_NB    = (N_NODES + SCAN_CHUNK - 1) / SCAN_CHUNK;  // 49

// ---------------------------------------------------------------------------
// CSR build: histogram of dst
// ---------------------------------------------------------------------------
__global__ __launch_bounds__(256) void k_hist(
    const int* __restrict__ dstv, int* __restrict__ counts)
{
    int e = blockIdx.x * blockDim.x + threadIdx.x;
    if (e < N_EDGES) atomicAdd(&counts[dstv[e]], 1);
}

// Scan pass A: per-chunk exclusive scan (chunk-local) + chunk totals
__global__ __launch_bounds__(256) void k_scanA(
    const int* __restrict__ counts, int* __restrict__ offsets,
    int* __restrict__ part)
{
    __shared__ int sdata[256];
    int t = threadIdx.x;
    int base = blockIdx.x * SCAN_CHUNK + t * 4;
    int a0 = (base + 0 < N_NODES) ? counts[base + 0] : 0;
    int a1 = (base + 1 < N_NODES) ? counts[base + 1] : 0;
    int a2 = (base + 2 < N_NODES) ? counts[base + 2] : 0;
    int a3 = (base + 3 < N_NODES) ? counts[base + 3] : 0;
    int s = a0 + a1 + a2 + a3;
    sdata[t] = s;
    __syncthreads();
    for (int off = 1; off < 256; off <<= 1) {
        int v = (t >= off) ? sdata[t - off] : 0;
        __syncthreads();
        sdata[t] += v;
        __syncthreads();
    }
    int excl = sdata[t] - s;
    int p = excl;
    if (base + 0 < N_NODES) { offsets[base + 0] = p; p += a0; }
    if (base + 1 < N_NODES) { offsets[base + 1] = p; p += a1; }
    if (base + 2 < N_NODES) { offsets[base + 2] = p; p += a2; }
    if (base + 3 < N_NODES) { offsets[base + 3] = p; }
    if (t == 255) part[blockIdx.x] = sdata[255];
}

// Scan pass B: exclusive scan of the 49 partials (single thread — trivial)
__global__ void k_scanB(int* __restrict__ part)
{
    if (threadIdx.x == 0 && blockIdx.x == 0) {
        int run = 0;
        for (int i = 0; i < SCAN_NB; ++i) { int v = part[i]; part[i] = run; run += v; }
        part[SCAN_NB] = run;
    }
}

// Scan pass C: add chunk offset; also init cursor and the final sentinel
__global__ __launch_bounds__(256) void k_scanC(
    int* __restrict__ offsets, int* __restrict__ cursor,
    const int* __restrict__ part)
{
    int t = threadIdx.x;
    int base = blockIdx.x * SCAN_CHUNK + t * 4;
    int add = part[blockIdx.x];
#pragma unroll
    for (int j = 0; j < 4; ++j) {
        int i = base + j;
        if (i < N_NODES) {
            int v = offsets[i] + add;
            offsets[i] = v;
            cursor[i]  = v;
        }
    }
    if (blockIdx.x == 0 && t == 0) offsets[N_NODES] = part[SCAN_NB];
}

// CSR fill: bucket src ids by dst
__global__ __launch_bounds__(256) void k_fill(
    const int* __restrict__ srcv, const int* __restrict__ dstv,
    int* __restrict__ cursor, int* __restrict__ esrc)
{
    int e = blockIdx.x * blockDim.x + threadIdx.x;
    if (e >= N_EDGES) return;
    int pos = atomicAdd(&cursor[dstv[e]], 1);
    esrc[pos] = srcv[e];
}

// ---------------------------------------------------------------------------
// Pre-projection layer 1: u1 = x @ Wrel1 ; r1 = x @ Wroot1 + b1   (both [N,64])
// Wave per row; weights in registers; row broadcast via shfl.
// ---------------------------------------------------------------------------
__global__ __launch_bounds__(256) void k_pre1(
    const float* __restrict__ x,
    const float* __restrict__ Wrel,    // [64][64]
    const float* __restrict__ Wroot,   // [64][64]
    const float* __restrict__ bias,    // [64]
    float* __restrict__ u1, float* __restrict__ r1)
{
    int lane = threadIdx.x & 63;
    float wl[64], wr[64];
#pragma unroll
    for (int k = 0; k < 64; ++k) {
        wl[k] = Wrel [k * 64 + lane];
        wr[k] = Wroot[k * 64 + lane];
    }
    float bv = bias[lane];

    int row = (blockIdx.x * blockDim.x + threadIdx.x) >> 6;
    if (row >= N_NODES) return;
    float xv = x[(size_t)row * 64 + lane];
    float su = 0.0f, sr = bv;
#pragma unroll
    for (int k = 0; k < 64; ++k) {
        float xk = __shfl(xv, k);
        su += xk * wl[k];
        sr += xk * wr[k];
    }
    u1[(size_t)row * 64 + lane] = su;
    r1[(size_t)row * 64 + lane] = sr;
}

// ---------------------------------------------------------------------------
// Aggregate layer 1: h[n] = relu( sum_{e in in(n)} u1[src_e] + r1[n] )
// Wave per node, float2 per lane, 2 edges per iteration (512B/instr).
// ---------------------------------------------------------------------------
__global__ __launch_bounds__(256) void k_agg64(
    const float* __restrict__ u1, const float* __restrict__ r1,
    const int* __restrict__ offsets, const int* __restrict__ esrc,
    float* __restrict__ h)
{
    int lane = threadIdx.x & 63;
    int node = (blockIdx.x * blockDim.x + threadIdx.x) >> 6;
    if (node >= N_NODES) return;
    int beg = offsets[node], end = offsets[node + 1];
    int half = lane >> 5;        // which edge of the pair
    int c2   = lane & 31;        // float2 channel-pair index (covers 64 ch)
    float ax = 0.0f, ay = 0.0f;
    for (int e = beg + half; e < end; e += 2) {
        int s = esrc[e];
        const float2 v = *reinterpret_cast<const float2*>(u1 + (size_t)s * 64 + c2 * 2);
        ax += v.x; ay += v.y;
    }
    ax += __shfl_xor(ax, 32);
    ay += __shfl_xor(ay, 32);
    if (lane < 32) {
        const float2 r = *reinterpret_cast<const float2*>(r1 + (size_t)node * 64 + c2 * 2);
        float2 o;
        o.x = fmaxf(ax + r.x, 0.0f);
        o.y = fmaxf(ay + r.y, 0.0f);
        *reinterpret_cast<float2*>(h + (size_t)node * 64 + c2 * 2) = o;
    }
}

// ---------------------------------------------------------------------------
// Pre-projection layer 2: u2 = h @ Wrel2 ; r2 = h @ Wroot2 + b2  (both [N,32])
// Lanes 0..31 produce u2 channels, lanes 32..63 produce r2 channels.
// ---------------------------------------------------------------------------
__global__ __launch_bounds__(256) void k_pre2(
    const float* __restrict__ h,
    const float* __restrict__ Wrel,    // [64][32]
    const float* __restrict__ Wroot,   // [64][32]
    const float* __restrict__ bias,    // [32]
    float* __restrict__ u2, float* __restrict__ r2)
{
    int lane = threadIdx.x & 63;
    int c    = lane & 31;
    bool isRoot = lane >= 32;
    float w[64];
#pragma unroll
    for (int k = 0; k < 64; ++k)
        w[k] = isRoot ? Wroot[k * 32 + c] : Wrel[k * 32 + c];
    float bv = isRoot ? bias[c] : 0.0f;

    int row = (blockIdx.x * blockDim.x + threadIdx.x) >> 6;
    if (row >= N_NODES) return;
    float hv = h[(size_t)row * 64 + lane];
    float sum = bv;
#pragma unroll
    for (int k = 0; k < 64; ++k) {
        float hk = __shfl(hv, k);
        sum += hk * w[k];
    }
    if (isRoot) r2[(size_t)row * 32 + c] = sum;
    else        u2[(size_t)row * 32 + c] = sum;
}

// ---------------------------------------------------------------------------
// Aggregate layer 2: out[n] = sum u2[src_e] + r2[n]   (32 channels)
// Wave per node, float2 per lane, 4 edges per iteration.
// ---------------------------------------------------------------------------
__global__ __launch_bounds__(256) void k_agg32(
    const float* __restrict__ u2, const float* __restrict__ r2,
    const int* __restrict__ offsets, const int* __restrict__ esrc,
    float* __restrict__ out)
{
    int lane = threadIdx.x & 63;
    int node = (blockIdx.x * blockDim.x + threadIdx.x) >> 6;
    if (node >= N_NODES) return;
    int beg = offsets[node], end = offsets[node + 1];
    int q  = lane >> 4;          // which edge of the quad
    int c2 = lane & 15;          // float2 pair index (covers 32 ch)
    float ax = 0.0f, ay = 0.0f;
    for (int e = beg + q; e < end; e += 4) {
        int s = esrc[e];
        const float2 v = *reinterpret_cast<const float2*>(u2 + (size_t)s * 32 + c2 * 2);
        ax += v.x; ay += v.y;
    }
    ax += __shfl_xor(ax, 32);
    ay += __shfl_xor(ay, 32);
    ax += __shfl_xor(ax, 16);
    ay += __shfl_xor(ay, 16);
    if (lane < 16) {
        const float2 r = *reinterpret_cast<const float2*>(r2 + (size_t)node * 32 + c2 * 2);
        float2 o;
        o.x = ax + r.x;
        o.y = ay + r.y;
        *reinterpret_cast<float2*>(out + (size_t)node * 32 + c2 * 2) = o;
    }
}

extern "C" void kernel_launch(void* const* d_in, const int* in_sizes, int n_in,
                              void* d_out, int out_size, void* d_ws, size_t ws_size,
                              hipStream_t stream) {
    const float* x      = (const float*)d_in[0];
    const int*   ei     = (const int*)  d_in[1];
    const float* Wrel1  = (const float*)d_in[2];
    const float* Wroot1 = (const float*)d_in[3];
    const float* b1     = (const float*)d_in[4];
    const float* Wrel2  = (const float*)d_in[5];
    const float* Wroot2 = (const float*)d_in[6];
    const float* b2     = (const float*)d_in[7];
    float*       out    = (float*)d_out;

    const int* srcv = ei;
    const int* dstv = ei + N_EDGES;

    // Workspace layout (all 256B-aligned)
    char* p = (char*)d_ws;
    auto alloc = [&](size_t bytes) {
        char* r = p;
        p += (bytes + 255) & ~(size_t)255;
        return r;
    };
    int*   counts  = (int*)  alloc(sizeof(int) * N_NODES);
    int*   offsets = (int*)  alloc(sizeof(int) * (N_NODES + 1));
    int*   cursor  = (int*)  alloc(sizeof(int) * N_NODES);
    int*   part    = (int*)  alloc(sizeof(int) * (SCAN_NB + 1));
    int*   esrc    = (int*)  alloc(sizeof(int) * N_EDGES);
    float* u1      = (float*)alloc(sizeof(float) * (size_t)N_NODES * 64);
    float* r1      = (float*)alloc(sizeof(float) * (size_t)N_NODES * 64);
    float* h       = (float*)alloc(sizeof(float) * (size_t)N_NODES * 64);
    float* u2      = u1;   // reuse after layer-1 aggregation consumed u1/r1
    float* r2      = r1;

    const int edgeBlocks = (N_EDGES + 255) / 256;
    const int rowBlocks  = (N_NODES * 64 + 255) / 256;   // wave per row

    // ---- CSR build (shared by both layers) ----
    hipMemsetAsync(counts, 0, sizeof(int) * N_NODES, stream);
    k_hist <<<edgeBlocks, 256, 0, stream>>>(dstv, counts);
    k_scanA<<<SCAN_NB,   256, 0, stream>>>(counts, offsets, part);
    k_scanB<<<1,          64, 0, stream>>>(part);
    k_scanC<<<SCAN_NB,   256, 0, stream>>>(offsets, cursor, part);
    k_fill <<<edgeBlocks, 256, 0, stream>>>(srcv, dstv, cursor, esrc);

    // ---- Layer 1 ----
    k_pre1 <<<rowBlocks, 256, 0, stream>>>(x, Wrel1, Wroot1, b1, u1, r1);
    k_agg64<<<rowBlocks, 256, 0, stream>>>(u1, r1, offsets, esrc, h);

    // ---- Layer 2 ----
    k_pre2 <<<rowBlocks, 256, 0, stream>>>(h, Wrel2, Wroot2, b2, u2, r2);
    k_agg32<<<rowBlocks, 256, 0, stream>>>(u2, r2, offsets, esrc, out);
}

// Round 3
// 240.831 us; speedup vs baseline: 2.3118x; 1.1383x over previous
//
#include <hip/hip_runtime.h>

static constexpr int N_NODES = 50000;
static constexpr int N_EDGES = 800000;

static constexpr int SCAN_CHUNK = 1024;                       // elems per block
static constexpr int SCAN_NB    = (N_NODES + SCAN_CHUNK - 1) / SCAN_CHUNK;  // 49

// ---------------------------------------------------------------------------
// CSR build: histogram of dst
// ---------------------------------------------------------------------------
__global__ __launch_bounds__(256) void k_hist(
    const int* __restrict__ dstv, int* __restrict__ counts)
{
    int e = blockIdx.x * blockDim.x + threadIdx.x;
    if (e < N_EDGES) atomicAdd(&counts[dstv[e]], 1);
}

// Scan pass A: per-chunk exclusive scan (chunk-local) + chunk totals
__global__ __launch_bounds__(256) void k_scanA(
    const int* __restrict__ counts, int* __restrict__ offsets,
    int* __restrict__ part)
{
    __shared__ int sdata[256];
    int t = threadIdx.x;
    int base = blockIdx.x * SCAN_CHUNK + t * 4;
    int a0 = (base + 0 < N_NODES) ? counts[base + 0] : 0;
    int a1 = (base + 1 < N_NODES) ? counts[base + 1] : 0;
    int a2 = (base + 2 < N_NODES) ? counts[base + 2] : 0;
    int a3 = (base + 3 < N_NODES) ? counts[base + 3] : 0;
    int s = a0 + a1 + a2 + a3;
    sdata[t] = s;
    __syncthreads();
    for (int off = 1; off < 256; off <<= 1) {
        int v = (t >= off) ? sdata[t - off] : 0;
        __syncthreads();
        sdata[t] += v;
        __syncthreads();
    }
    int excl = sdata[t] - s;
    int p = excl;
    if (base + 0 < N_NODES) { offsets[base + 0] = p; p += a0; }
    if (base + 1 < N_NODES) { offsets[base + 1] = p; p += a1; }
    if (base + 2 < N_NODES) { offsets[base + 2] = p; p += a2; }
    if (base + 3 < N_NODES) { offsets[base + 3] = p; }
    if (t == 255) part[blockIdx.x] = sdata[255];
}

// Scan pass B: exclusive scan of the 49 partials
__global__ void k_scanB(int* __restrict__ part)
{
    if (threadIdx.x == 0 && blockIdx.x == 0) {
        int run = 0;
        for (int i = 0; i < SCAN_NB; ++i) { int v = part[i]; part[i] = run; run += v; }
        part[SCAN_NB] = run;
    }
}

// Scan pass C: add chunk offset; init cursor and final sentinel
__global__ __launch_bounds__(256) void k_scanC(
    int* __restrict__ offsets, int* __restrict__ cursor,
    const int* __restrict__ part)
{
    int t = threadIdx.x;
    int base = blockIdx.x * SCAN_CHUNK + t * 4;
    int add = part[blockIdx.x];
#pragma unroll
    for (int j = 0; j < 4; ++j) {
        int i = base + j;
        if (i < N_NODES) {
            int v = offsets[i] + add;
            offsets[i] = v;
            cursor[i]  = v;
        }
    }
    if (blockIdx.x == 0 && t == 0) offsets[N_NODES] = part[SCAN_NB];
}

// CSR fill: bucket src ids by dst
__global__ __launch_bounds__(256) void k_fill(
    const int* __restrict__ srcv, const int* __restrict__ dstv,
    int* __restrict__ cursor, int* __restrict__ esrc)
{
    int e = blockIdx.x * blockDim.x + threadIdx.x;
    if (e >= N_EDGES) return;
    int pos = atomicAdd(&cursor[dstv[e]], 1);
    esrc[pos] = srcv[e];
}

// ---------------------------------------------------------------------------
// Pre-projection layer 1: u1 = x @ Wrel1 ; r1 = x @ Wroot1 + b1   (both [N,64])
// Wave per row, GRID-STRIDE so the 128 in-register weights amortize over
// ~16 rows/wave. One shfl broadcast feeds two FMAs.
// ---------------------------------------------------------------------------
__global__ __launch_bounds__(256) void k_pre1(
    const float* __restrict__ x,
    const float* __restrict__ Wrel,    // [64][64]
    const float* __restrict__ Wroot,   // [64][64]
    const float* __restrict__ bias,    // [64]
    float* __restrict__ u1, float* __restrict__ r1)
{
    int lane = threadIdx.x & 63;
    float wl[64], wr[64];
#pragma unroll
    for (int k = 0; k < 64; ++k) {
        wl[k] = Wrel [k * 64 + lane];
        wr[k] = Wroot[k * 64 + lane];
    }
    float bv = bias[lane];

    int wid    = (blockIdx.x * blockDim.x + threadIdx.x) >> 6;
    int nwaves = (gridDim.x * blockDim.x) >> 6;
    for (int row = wid; row < N_NODES; row += nwaves) {
        float xv = x[(size_t)row * 64 + lane];
        float su = 0.0f, sr = bv;
#pragma unroll
        for (int k = 0; k < 64; ++k) {
            float xk = __shfl(xv, k);
            su += xk * wl[k];
            sr += xk * wr[k];
        }
        u1[(size_t)row * 64 + lane] = su;
        r1[(size_t)row * 64 + lane] = sr;
    }
}

// ---------------------------------------------------------------------------
// Aggregate layer 1: h[n] = relu( sum_{e in in(n)} u1[src_e] + r1[n] )
// Wave per node; float4 per lane; 16-lane channel groups -> 4 edges in flight.
// ---------------------------------------------------------------------------
__global__ __launch_bounds__(256) void k_agg64(
    const float* __restrict__ u1, const float* __restrict__ r1,
    const int* __restrict__ offsets, const int* __restrict__ esrc,
    float* __restrict__ h)
{
    int lane = threadIdx.x & 63;
    int node = (blockIdx.x * blockDim.x + threadIdx.x) >> 6;
    if (node >= N_NODES) return;
    int beg = offsets[node], end = offsets[node + 1];
    int g  = lane >> 4;          // edge slot 0..3
    int c4 = lane & 15;          // float4 index (16 x 4 = 64 channels)
    float ax = 0.0f, ay = 0.0f, az = 0.0f, aw = 0.0f;
    for (int e = beg + g; e < end; e += 4) {
        int s = esrc[e];
        const float4 v = *reinterpret_cast<const float4*>(u1 + (size_t)s * 64 + c4 * 4);
        ax += v.x; ay += v.y; az += v.z; aw += v.w;
    }
    ax += __shfl_xor(ax, 32); ay += __shfl_xor(ay, 32);
    az += __shfl_xor(az, 32); aw += __shfl_xor(aw, 32);
    ax += __shfl_xor(ax, 16); ay += __shfl_xor(ay, 16);
    az += __shfl_xor(az, 16); aw += __shfl_xor(aw, 16);
    if (lane < 16) {
        const float4 r = *reinterpret_cast<const float4*>(r1 + (size_t)node * 64 + c4 * 4);
        float4 o;
        o.x = fmaxf(ax + r.x, 0.0f);
        o.y = fmaxf(ay + r.y, 0.0f);
        o.z = fmaxf(az + r.z, 0.0f);
        o.w = fmaxf(aw + r.w, 0.0f);
        *reinterpret_cast<float4*>(h + (size_t)node * 64 + c4 * 4) = o;
    }
}

// ---------------------------------------------------------------------------
// Pre-projection layer 2: u2 = h @ Wrel2 ; r2 = h @ Wroot2 + b2  (both [N,32])
// Lanes 0..31 -> u2 channels, lanes 32..63 -> r2 channels. Grid-stride.
// ---------------------------------------------------------------------------
__global__ __launch_bounds__(256) void k_pre2(
    const float* __restrict__ h,
    const float* __restrict__ Wrel,    // [64][32]
    const float* __restrict__ Wroot,   // [64][32]
    const float* __restrict__ bias,    // [32]
    float* __restrict__ u2, float* __restrict__ r2)
{
    int lane = threadIdx.x & 63;
    int c    = lane & 31;
    bool isRoot = lane >= 32;
    float w[64];
#pragma unroll
    for (int k = 0; k < 64; ++k)
        w[k] = isRoot ? Wroot[k * 32 + c] : Wrel[k * 32 + c];
    float bv = isRoot ? bias[c] : 0.0f;

    int wid    = (blockIdx.x * blockDim.x + threadIdx.x) >> 6;
    int nwaves = (gridDim.x * blockDim.x) >> 6;
    for (int row = wid; row < N_NODES; row += nwaves) {
        float hv = h[(size_t)row * 64 + lane];
        float sum = bv;
#pragma unroll
        for (int k = 0; k < 64; ++k) {
            float hk = __shfl(hv, k);
            sum += hk * w[k];
        }
        if (isRoot) r2[(size_t)row * 32 + c] = sum;
        else        u2[(size_t)row * 32 + c] = sum;
    }
}

// ---------------------------------------------------------------------------
// Aggregate layer 2: out[n] = sum u2[src_e] + r2[n]   (32 channels)
// Wave per node; float4 per lane; 8-lane channel groups -> 8 edges in flight.
// ---------------------------------------------------------------------------
__global__ __launch_bounds__(256) void k_agg32(
    const float* __restrict__ u2, const float* __restrict__ r2,
    const int* __restrict__ offsets, const int* __restrict__ esrc,
    float* __restrict__ out)
{
    int lane = threadIdx.x & 63;
    int node = (blockIdx.x * blockDim.x + threadIdx.x) >> 6;
    if (node >= N_NODES) return;
    int beg = offsets[node], end = offsets[node + 1];
    int g  = lane >> 3;          // edge slot 0..7
    int c4 = lane & 7;           // float4 index (8 x 4 = 32 channels)
    float ax = 0.0f, ay = 0.0f, az = 0.0f, aw = 0.0f;
    for (int e = beg + g; e < end; e += 8) {
        int s = esrc[e];
        const float4 v = *reinterpret_cast<const float4*>(u2 + (size_t)s * 32 + c4 * 4);
        ax += v.x; ay += v.y; az += v.z; aw += v.w;
    }
    ax += __shfl_xor(ax, 32); ay += __shfl_xor(ay, 32);
    az += __shfl_xor(az, 32); aw += __shfl_xor(aw, 32);
    ax += __shfl_xor(ax, 16); ay += __shfl_xor(ay, 16);
    az += __shfl_xor(az, 16); aw += __shfl_xor(aw, 16);
    ax += __shfl_xor(ax, 8);  ay += __shfl_xor(ay, 8);
    az += __shfl_xor(az, 8);  aw += __shfl_xor(aw, 8);
    if (lane < 8) {
        const float4 r = *reinterpret_cast<const float4*>(r2 + (size_t)node * 32 + c4 * 4);
        float4 o;
        o.x = ax + r.x;
        o.y = ay + r.y;
        o.z = az + r.z;
        o.w = aw + r.w;
        *reinterpret_cast<float4*>(out + (size_t)node * 32 + c4 * 4) = o;
    }
}

extern "C" void kernel_launch(void* const* d_in, const int* in_sizes, int n_in,
                              void* d_out, int out_size, void* d_ws, size_t ws_size,
                              hipStream_t stream) {
    const float* x      = (const float*)d_in[0];
    const int*   ei     = (const int*)  d_in[1];
    const float* Wrel1  = (const float*)d_in[2];
    const float* Wroot1 = (const float*)d_in[3];
    const float* b1     = (const float*)d_in[4];
    const float* Wrel2  = (const float*)d_in[5];
    const float* Wroot2 = (const float*)d_in[6];
    const float* b2     = (const float*)d_in[7];
    float*       out    = (float*)d_out;

    const int* srcv = ei;
    const int* dstv = ei + N_EDGES;

    // Workspace layout (all 256B-aligned)
    char* p = (char*)d_ws;
    auto alloc = [&](size_t bytes) {
        char* r = p;
        p += (bytes + 255) & ~(size_t)255;
        return r;
    };
    int*   counts  = (int*)  alloc(sizeof(int) * N_NODES);
    int*   offsets = (int*)  alloc(sizeof(int) * (N_NODES + 1));
    int*   cursor  = (int*)  alloc(sizeof(int) * N_NODES);
    int*   part    = (int*)  alloc(sizeof(int) * (SCAN_NB + 1));
    int*   esrc    = (int*)  alloc(sizeof(int) * N_EDGES);
    float* u1      = (float*)alloc(sizeof(float) * (size_t)N_NODES * 64);
    float* r1      = (float*)alloc(sizeof(float) * (size_t)N_NODES * 64);
    float* h       = (float*)alloc(sizeof(float) * (size_t)N_NODES * 64);
    float* u2      = u1;   // reuse after layer-1 aggregation consumed u1/r1
    float* r2      = r1;

    const int edgeBlocks = (N_EDGES + 255) / 256;
    const int aggBlocks  = (N_NODES * 64 + 255) / 256;   // wave per node

    // ---- CSR build (shared by both layers) ----
    hipMemsetAsync(counts, 0, sizeof(int) * N_NODES, stream);
    k_hist <<<edgeBlocks, 256, 0, stream>>>(dstv, counts);
    k_scanA<<<SCAN_NB,   256, 0, stream>>>(counts, offsets, part);
    k_scanB<<<1,          64, 0, stream>>>(part);
    k_scanC<<<SCAN_NB,   256, 0, stream>>>(offsets, cursor, part);
    k_fill <<<edgeBlocks, 256, 0, stream>>>(srcv, dstv, cursor, esrc);

    // ---- Layer 1 ----
    k_pre1 <<<768,  256, 0, stream>>>(x, Wrel1, Wroot1, b1, u1, r1);
    k_agg64<<<aggBlocks, 256, 0, stream>>>(u1, r1, offsets, esrc, h);

    // ---- Layer 2 ----
    k_pre2 <<<1280, 256, 0, stream>>>(h, Wrel2, Wroot2, b2, u2, r2);
    k_agg32<<<aggBlocks, 256, 0, stream>>>(u2, r2, offsets, esrc, out);
}

// Round 4
// 183.242 us; speedup vs baseline: 3.0384x; 1.3143x over previous
//
#include <hip/hip_runtime.h>

static constexpr int N_NODES = 50000;
static constexpr int N_EDGES = 800000;

static constexpr int SCAN_CHUNK = 1024;
static constexpr int SCAN_NB    = (N_NODES + SCAN_CHUNK - 1) / SCAN_CHUNK;  // 49

typedef __attribute__((ext_vector_type(8))) short   bf16x8;
typedef __attribute__((ext_vector_type(4))) float   floatx4;

// f32 -> bf16 (RNE) as raw u16
__device__ __forceinline__ unsigned short f2b(float f) {
    union { float f; unsigned u; } v; v.f = f;
    unsigned r = v.u + 0x7FFFu + ((v.u >> 16) & 1u);
    return (unsigned short)(r >> 16);
}
__device__ __forceinline__ float blo(unsigned v) {
    union { unsigned u; float f; } c; c.u = v << 16; return c.f;
}
__device__ __forceinline__ float bhi(unsigned v) {
    union { unsigned u; float f; } c; c.u = v & 0xffff0000u; return c.f;
}
__device__ __forceinline__ unsigned pk2(float a, float b) {
    return (unsigned)f2b(a) | ((unsigned)f2b(b) << 16);
}

// ---------------------------------------------------------------------------
// CSR build
// ---------------------------------------------------------------------------
__global__ __launch_bounds__(256) void k_hist(
    const int* __restrict__ dstv, int* __restrict__ counts)
{
    int e = blockIdx.x * blockDim.x + threadIdx.x;
    if (e < N_EDGES) atomicAdd(&counts[dstv[e]], 1);
}

__global__ __launch_bounds__(256) void k_scanA(
    const int* __restrict__ counts, int* __restrict__ offsets,
    int* __restrict__ part)
{
    __shared__ int sdata[256];
    int t = threadIdx.x;
    int base = blockIdx.x * SCAN_CHUNK + t * 4;
    int a0 = (base + 0 < N_NODES) ? counts[base + 0] : 0;
    int a1 = (base + 1 < N_NODES) ? counts[base + 1] : 0;
    int a2 = (base + 2 < N_NODES) ? counts[base + 2] : 0;
    int a3 = (base + 3 < N_NODES) ? counts[base + 3] : 0;
    int s = a0 + a1 + a2 + a3;
    sdata[t] = s;
    __syncthreads();
    for (int off = 1; off < 256; off <<= 1) {
        int v = (t >= off) ? sdata[t - off] : 0;
        __syncthreads();
        sdata[t] += v;
        __syncthreads();
    }
    int p = sdata[t] - s;
    if (base + 0 < N_NODES) { offsets[base + 0] = p; p += a0; }
    if (base + 1 < N_NODES) { offsets[base + 1] = p; p += a1; }
    if (base + 2 < N_NODES) { offsets[base + 2] = p; p += a2; }
    if (base + 3 < N_NODES) { offsets[base + 3] = p; }
    if (t == 255) part[blockIdx.x] = sdata[255];
}

// scanC with fused partial-scan: each block wave-reduces its own prefix.
__global__ __launch_bounds__(256) void k_scanC(
    int* __restrict__ offsets, int* __restrict__ cursor,
    const int* __restrict__ part)
{
    __shared__ int s_add, s_tot;
    int t = threadIdx.x;
    if (t < 64) {
        int v   = (t < SCAN_NB) ? part[t] : 0;
        int pre = (t < (int)blockIdx.x) ? v : 0;
        for (int off = 1; off < 64; off <<= 1) {
            pre += __shfl_xor(pre, off);
            v   += __shfl_xor(v, off);
        }
        if (t == 0) { s_add = pre; s_tot = v; }
    }
    __syncthreads();
    int add = s_add;
    int base = blockIdx.x * SCAN_CHUNK + t * 4;
#pragma unroll
    for (int j = 0; j < 4; ++j) {
        int i = base + j;
        if (i < N_NODES) {
            int v = offsets[i] + add;
            offsets[i] = v;
            cursor[i]  = v;
        }
    }
    if (blockIdx.x == 0 && t == 0) offsets[N_NODES] = s_tot;
}

__global__ __launch_bounds__(256) void k_fill(
    const int* __restrict__ srcv, const int* __restrict__ dstv,
    int* __restrict__ cursor, int* __restrict__ esrc)
{
    int e = blockIdx.x * blockDim.x + threadIdx.x;
    if (e >= N_EDGES) return;
    int pos = atomicAdd(&cursor[dstv[e]], 1);
    esrc[pos] = srcv[e];
}

// ---------------------------------------------------------------------------
// Layer-1 pre-projection (MFMA): u1 = x@Wrel1 (bf16), r1 = x@Wroot1+b1 (bf16)
// Both stored [N][64] bf16 in sigma-order: position p = (lane&15)*4 + ct,
// true col = ct*16 + (lane&15)  =>  sigma(p) = (p&3)*16 + (p>>2).
// One 16-row tile per wave. No LDS.
// ---------------------------------------------------------------------------
__global__ __launch_bounds__(256) void k_pre1(
    const float* __restrict__ x,
    const float* __restrict__ Wrel,    // [64][64] f32
    const float* __restrict__ Wroot,   // [64][64] f32
    const float* __restrict__ bias,    // [64] f32
    unsigned short* __restrict__ u1,
    unsigned short* __restrict__ r1)
{
    int lane = threadIdx.x & 63;
    int c15  = lane & 15;
    int q    = lane >> 4;

    // B-frag preload: [mat][ct][kf], B col = lane&15, k = kf*32 + q*8 + j
    bf16x8 bf[2][4][2];
#pragma unroll
    for (int mat = 0; mat < 2; ++mat) {
        const float* W = mat ? Wroot : Wrel;
#pragma unroll
        for (int ct = 0; ct < 4; ++ct) {
            int c = ct * 16 + c15;
#pragma unroll
            for (int kf = 0; kf < 2; ++kf) {
                int kb = kf * 32 + q * 8;
                bf16x8 f;
#pragma unroll
                for (int j = 0; j < 8; ++j)
                    f[j] = (short)f2b(W[(kb + j) * 64 + c]);
                bf[mat][ct][kf] = f;
            }
        }
    }
    float bv[4];
#pragma unroll
    for (int ct = 0; ct < 4; ++ct) bv[ct] = bias[ct * 16 + c15];

    int tile = (blockIdx.x * blockDim.x + threadIdx.x) >> 6;
    if (tile * 16 >= N_NODES) return;
    int row0 = tile * 16;

    // A-frags: row = lane&15, k = q*8 + j (+32 for frag1); f32 -> bf16
    const float* xr = x + (size_t)(row0 + c15) * 64;
    bf16x8 a0, a1;
#pragma unroll
    for (int j = 0; j < 8; ++j) {
        a0[j] = (short)f2b(xr[q * 8 + j]);
        a1[j] = (short)f2b(xr[32 + q * 8 + j]);
    }

    floatx4 z = {0.f, 0.f, 0.f, 0.f};
    floatx4 acc[2][4];
#pragma unroll
    for (int mat = 0; mat < 2; ++mat)
#pragma unroll
        for (int ct = 0; ct < 4; ++ct) {
            floatx4 a = __builtin_amdgcn_mfma_f32_16x16x32_bf16(a0, bf[mat][ct][0], z, 0, 0, 0);
            acc[mat][ct] = __builtin_amdgcn_mfma_f32_16x16x32_bf16(a1, bf[mat][ct][1], a, 0, 0, 0);
        }

    // Epilogue: C row = q*4 + reg, col = ct*16 + c15. Write sigma-order rows:
    // 8B per lane per matrix per reg -> fully coalesced 128B rows.
#pragma unroll
    for (int reg = 0; reg < 4; ++reg) {
        int row = row0 + q * 4 + reg;
        uint2 uu, rr;
        uu.x = pk2(acc[0][0][reg],          acc[0][1][reg]);
        uu.y = pk2(acc[0][2][reg],          acc[0][3][reg]);
        rr.x = pk2(acc[1][0][reg] + bv[0],  acc[1][1][reg] + bv[1]);
        rr.y = pk2(acc[1][2][reg] + bv[2],  acc[1][3][reg] + bv[3]);
        *reinterpret_cast<uint2*>(u1 + (size_t)row * 64 + c15 * 4) = uu;
        *reinterpret_cast<uint2*>(r1 + (size_t)row * 64 + c15 * 4) = rr;
    }
}

// ---------------------------------------------------------------------------
// Aggregate layer 1: h[n] = relu( sum_e u1[src_e] + r1[n] ), all sigma-order
// bf16. Wave per node; 16 lanes x 8B per edge; 4 edge slots.
// ---------------------------------------------------------------------------
__global__ __launch_bounds__(256) void k_agg64(
    const unsigned short* __restrict__ u1,
    const unsigned short* __restrict__ r1,
    const int* __restrict__ offsets, const int* __restrict__ esrc,
    unsigned short* __restrict__ h)
{
    int lane = threadIdx.x & 63;
    int node = (blockIdx.x * blockDim.x + threadIdx.x) >> 6;
    if (node >= N_NODES) return;
    int j    = lane & 15;
    int slot = lane >> 4;
    int beg = offsets[node], end = offsets[node + 1];
    float s0 = 0.f, s1 = 0.f, s2 = 0.f, s3 = 0.f;
    for (int e = beg + slot; e < end; e += 4) {
        int s = esrc[e];
        uint2 v = *reinterpret_cast<const uint2*>(u1 + (size_t)s * 64 + j * 4);
        s0 += blo(v.x); s1 += bhi(v.x);
        s2 += blo(v.y); s3 += bhi(v.y);
    }
    s0 += __shfl_xor(s0, 32); s1 += __shfl_xor(s1, 32);
    s2 += __shfl_xor(s2, 32); s3 += __shfl_xor(s3, 32);
    s0 += __shfl_xor(s0, 16); s1 += __shfl_xor(s1, 16);
    s2 += __shfl_xor(s2, 16); s3 += __shfl_xor(s3, 16);
    if (lane < 16) {
        uint2 rv = *reinterpret_cast<const uint2*>(r1 + (size_t)node * 64 + j * 4);
        float v0 = fmaxf(s0 + blo(rv.x), 0.f);
        float v1 = fmaxf(s1 + bhi(rv.x), 0.f);
        float v2 = fmaxf(s2 + blo(rv.y), 0.f);
        float v3 = fmaxf(s3 + bhi(rv.y), 0.f);
        uint2 o; o.x = pk2(v0, v1); o.y = pk2(v2, v3);
        *reinterpret_cast<uint2*>(h + (size_t)node * 64 + j * 4) = o;
    }
}

// ---------------------------------------------------------------------------
// Layer-2 pre-projection (MFMA): u2 = h@Wrel2 (bf16), r2 = h@Wroot2+b2 (bf16)
// h is sigma-order bf16 -> A-frags load directly (16B). W2's K rows are
// permuted by sigma to compensate. Outputs [N][32] bf16 in sigma2-order:
// p = (lane&15)*2 + ct, true col = ct*16 + (lane&15).
// ---------------------------------------------------------------------------
__global__ __launch_bounds__(256) void k_pre2(
    const unsigned short* __restrict__ h,
    const float* __restrict__ Wrel,    // [64][32] f32
    const float* __restrict__ Wroot,   // [64][32] f32
    const float* __restrict__ bias,    // [32] f32
    unsigned short* __restrict__ u2,
    unsigned short* __restrict__ r2)
{
    int lane = threadIdx.x & 63;
    int c15  = lane & 15;
    int q    = lane >> 4;

    bf16x8 bf[2][2][2];   // [mat][ct][kf]
#pragma unroll
    for (int mat = 0; mat < 2; ++mat) {
        const float* W = mat ? Wroot : Wrel;
#pragma unroll
        for (int ct = 0; ct < 2; ++ct) {
            int c = ct * 16 + c15;
#pragma unroll
            for (int kf = 0; kf < 2; ++kf) {
                bf16x8 f;
#pragma unroll
                for (int j = 0; j < 8; ++j) {
                    int p = kf * 32 + q * 8 + j;
                    int tk = (p & 3) * 16 + (p >> 2);   // sigma(p)
                    f[j] = (short)f2b(W[tk * 32 + c]);
                }
                bf[mat][ct][kf] = f;
            }
        }
    }
    float bv[2];
#pragma unroll
    for (int ct = 0; ct < 2; ++ct) bv[ct] = bias[ct * 16 + c15];

    int tile = (blockIdx.x * blockDim.x + threadIdx.x) >> 6;
    if (tile * 16 >= N_NODES) return;
    int row0 = tile * 16;

    const unsigned short* hr = h + (size_t)(row0 + c15) * 64;
    bf16x8 a0 = *reinterpret_cast<const bf16x8*>(hr + q * 8);
    bf16x8 a1 = *reinterpret_cast<const bf16x8*>(hr + 32 + q * 8);

    floatx4 z = {0.f, 0.f, 0.f, 0.f};
    floatx4 acc[2][2];
#pragma unroll
    for (int mat = 0; mat < 2; ++mat)
#pragma unroll
        for (int ct = 0; ct < 2; ++ct) {
            floatx4 a = __builtin_amdgcn_mfma_f32_16x16x32_bf16(a0, bf[mat][ct][0], z, 0, 0, 0);
            acc[mat][ct] = __builtin_amdgcn_mfma_f32_16x16x32_bf16(a1, bf[mat][ct][1], a, 0, 0, 0);
        }

#pragma unroll
    for (int reg = 0; reg < 4; ++reg) {
        int row = row0 + q * 4 + reg;
        unsigned uu = pk2(acc[0][0][reg],         acc[0][1][reg]);
        unsigned rr = pk2(acc[1][0][reg] + bv[0], acc[1][1][reg] + bv[1]);
        *reinterpret_cast<unsigned*>(u2 + (size_t)row * 32 + c15 * 2) = uu;
        *reinterpret_cast<unsigned*>(r2 + (size_t)row * 32 + c15 * 2) = rr;
    }
}

// ---------------------------------------------------------------------------
// Aggregate layer 2: out[n] = sum_e u2[src_e] + r2[n]; out is TRUE row-major
// f32 [N][32]. Lane j holds true cols {j, 16+j}.
// ---------------------------------------------------------------------------
__global__ __launch_bounds__(256) void k_agg32(
    const unsigned short* __restrict__ u2,
    const unsigned short* __restrict__ r2,
    const int* __restrict__ offsets, const int* __restrict__ esrc,
    float* __restrict__ out)
{
    int lane = threadIdx.x & 63;
    int node = (blockIdx.x * blockDim.x + threadIdx.x) >> 6;
    if (node >= N_NODES) return;
    int j    = lane & 15;
    int slot = lane >> 4;
    int beg = offsets[node], end = offsets[node + 1];
    float s0 = 0.f, s1 = 0.f;
    for (int e = beg + slot; e < end; e += 4) {
        int s = esrc[e];
        unsigned v = *reinterpret_cast<const unsigned*>(u2 + (size_t)s * 32 + j * 2);
        s0 += blo(v); s1 += bhi(v);
    }
    s0 += __shfl_xor(s0, 32); s1 += __shfl_xor(s1, 32);
    s0 += __shfl_xor(s0, 16); s1 += __shfl_xor(s1, 16);
    if (lane < 16) {
        unsigned rv = *reinterpret_cast<const unsigned*>(r2 + (size_t)node * 32 + j * 2);
        out[(size_t)node * 32 + j]      = s0 + blo(rv);
        out[(size_t)node * 32 + 16 + j] = s1 + bhi(rv);
    }
}

extern "C" void kernel_launch(void* const* d_in, const int* in_sizes, int n_in,
                              void* d_out, int out_size, void* d_ws, size_t ws_size,
                              hipStream_t stream) {
    const float* x      = (const float*)d_in[0];
    const int*   ei     = (const int*)  d_in[1];
    const float* Wrel1  = (const float*)d_in[2];
    const float* Wroot1 = (const float*)d_in[3];
    const float* b1     = (const float*)d_in[4];
    const float* Wrel2  = (const float*)d_in[5];
    const float* Wroot2 = (const float*)d_in[6];
    const float* b2     = (const float*)d_in[7];
    float*       out    = (float*)d_out;

    const int* srcv = ei;
    const int* dstv = ei + N_EDGES;

    char* p = (char*)d_ws;
    auto alloc = [&](size_t bytes) {
        char* r = p;
        p += (bytes + 255) & ~(size_t)255;
        return r;
    };
    int* counts  = (int*)alloc(sizeof(int) * N_NODES);
    int* offsets = (int*)alloc(sizeof(int) * (N_NODES + 1));
    int* cursor  = (int*)alloc(sizeof(int) * N_NODES);
    int* part    = (int*)alloc(sizeof(int) * SCAN_NB);
    int* esrc    = (int*)alloc(sizeof(int) * N_EDGES);
    unsigned short* u1 = (unsigned short*)alloc(sizeof(short) * (size_t)N_NODES * 64);
    unsigned short* r1 = (unsigned short*)alloc(sizeof(short) * (size_t)N_NODES * 64);
    unsigned short* h  = (unsigned short*)alloc(sizeof(short) * (size_t)N_NODES * 64);
    unsigned short* u2 = u1;   // reuse: u1/r1 dead after k_agg64
    unsigned short* r2 = r1;

    const int edgeBlocks = (N_EDGES + 255) / 256;
    const int nodeBlocks = (N_NODES * 64 + 255) / 256;      // wave per node
    const int tileBlocks = ((N_NODES / 16) + 3) / 4;        // wave per 16-row tile

    // CSR build
    hipMemsetAsync(counts, 0, sizeof(int) * N_NODES, stream);
    k_hist <<<edgeBlocks, 256, 0, stream>>>(dstv, counts);
    k_scanA<<<SCAN_NB,   256, 0, stream>>>(counts, offsets, part);
    k_scanC<<<SCAN_NB,   256, 0, stream>>>(offsets, cursor, part);
    k_fill <<<edgeBlocks, 256, 0, stream>>>(srcv, dstv, cursor, esrc);

    // Layer 1
    k_pre1 <<<tileBlocks, 256, 0, stream>>>(x, Wrel1, Wroot1, b1, u1, r1);
    k_agg64<<<nodeBlocks, 256, 0, stream>>>(u1, r1, offsets, esrc, h);

    // Layer 2
    k_pre2 <<<tileBlocks, 256, 0, stream>>>(h, Wrel2, Wroot2, b2, u2, r2);
    k_agg32<<<nodeBlocks, 256, 0, stream>>>(u2, r2, offsets, esrc, out);
}

// Round 5
// 156.687 us; speedup vs baseline: 3.5533x; 1.1695x over previous
//
#include <hip/hip_runtime.h>

static constexpr int N_NODES = 50000;
static constexpr int N_EDGES = 800000;

static constexpr int SCAN_CHUNK = 1024;
static constexpr int SCAN_NB    = (N_NODES + SCAN_CHUNK - 1) / SCAN_CHUNK;  // 49

static constexpr int NBK      = 98;      // buckets of 512 dst-nodes (dst>>9)
static constexpr int BCAP     = 10240;   // slots per bucket (mean 8163, +23 sigma)
static constexpr int BIN_TILE = 2048;    // edges per k_bin block

typedef __attribute__((ext_vector_type(8))) short   bf16x8;
typedef __attribute__((ext_vector_type(4))) float   floatx4;

// f32 -> bf16 (RNE) as raw u16
__device__ __forceinline__ unsigned short f2b(float f) {
    union { float f; unsigned u; } v; v.f = f;
    unsigned r = v.u + 0x7FFFu + ((v.u >> 16) & 1u);
    return (unsigned short)(r >> 16);
}
__device__ __forceinline__ float blo(unsigned v) {
    union { unsigned u; float f; } c; c.u = v << 16; return c.f;
}
__device__ __forceinline__ float bhi(unsigned v) {
    union { unsigned u; float f; } c; c.u = v & 0xffff0000u; return c.f;
}
__device__ __forceinline__ unsigned pk2(float a, float b) {
    return (unsigned)f2b(a) | ((unsigned)f2b(b) << 16);
}

// ---------------------------------------------------------------------------
// Init: zero dst-histogram, seed bucket cursors (replaces memset; 1 dispatch)
// ---------------------------------------------------------------------------
__global__ __launch_bounds__(256) void k_init(
    int* __restrict__ counts, int* __restrict__ bcur)
{
    int i = blockIdx.x * 256 + threadIdx.x;
    if (i < N_NODES) counts[i] = 0;
    if (i < NBK) bcur[i] = i * BCAP;
}

// ---------------------------------------------------------------------------
// Phase 1: bin edges into 98 dst-buckets with COALESCED writes (LDS staging),
// fused dst-histogram. epair[bucket region] gets (src,dst) pairs.
// ---------------------------------------------------------------------------
__global__ __launch_bounds__(256) void k_bin(
    const int* __restrict__ srcv, const int* __restrict__ dstv,
    int* __restrict__ counts, int* __restrict__ bcur,
    uint2* __restrict__ epair)
{
    __shared__ uint2 stage[BIN_TILE];      // 16 KB
    __shared__ int cnt[128];               // bucket counts (padded to 128)
    __shared__ int scn[128];
    __shared__ int pref[NBK];
    __shared__ int gbase[NBK];

    int tid   = threadIdx.x;
    int base  = blockIdx.x * BIN_TILE;
    int tileN = min(BIN_TILE, N_EDGES - base);

    if (tid < 128) cnt[tid] = 0;
    __syncthreads();

    int ss[8], dd[8], sl[8];
#pragma unroll
    for (int j = 0; j < 8; ++j) {
        int i = tid + j * 256;
        ss[j] = -1; dd[j] = 0; sl[j] = 0;
        if (i < tileN) {
            int s = srcv[base + i];
            int d = dstv[base + i];
            ss[j] = s; dd[j] = d;
            atomicAdd(&counts[d], 1);              // fused histogram
            sl[j] = atomicAdd(&cnt[d >> 9], 1);    // slot within bucket
        }
    }
    __syncthreads();

    // exclusive scan of cnt[0..127] (Hillis-Steele)
    int own = (tid < 128) ? cnt[tid] : 0;
    if (tid < 128) scn[tid] = own;
    __syncthreads();
    for (int off = 1; off < 128; off <<= 1) {
        int t = 0;
        if (tid < 128 && tid >= off) t = scn[tid - off];
        __syncthreads();
        if (tid < 128) scn[tid] += t;
        __syncthreads();
    }
    if (tid < NBK) {
        pref[tid]  = scn[tid] - cnt[tid];
        gbase[tid] = atomicAdd(&bcur[tid], cnt[tid]);
    }
    __syncthreads();

    // scatter pairs into LDS grouped by bucket
#pragma unroll
    for (int j = 0; j < 8; ++j) {
        if (ss[j] >= 0) {
            int b = dd[j] >> 9;
            stage[pref[b] + sl[j]] = uint2{(unsigned)ss[j], (unsigned)dd[j]};
        }
    }
    __syncthreads();

    // copy out: consecutive LDS slots -> consecutive global slots per bucket
    for (int i = tid; i < tileN; i += 256) {
        uint2 pd = stage[i];
        int b = (int)(pd.y >> 9);
        epair[(size_t)gbase[b] + (i - pref[b])] = pd;
    }
}

// ---------------------------------------------------------------------------
// Scan pass A: per-chunk exclusive scan of counts + chunk totals
// ---------------------------------------------------------------------------
__global__ __launch_bounds__(256) void k_scanA(
    const int* __restrict__ counts, int* __restrict__ offsets,
    int* __restrict__ part)
{
    __shared__ int sdata[256];
    int t = threadIdx.x;
    int base = blockIdx.x * SCAN_CHUNK + t * 4;
    int a0 = (base + 0 < N_NODES) ? counts[base + 0] : 0;
    int a1 = (base + 1 < N_NODES) ? counts[base + 1] : 0;
    int a2 = (base + 2 < N_NODES) ? counts[base + 2] : 0;
    int a3 = (base + 3 < N_NODES) ? counts[base + 3] : 0;
    int s = a0 + a1 + a2 + a3;
    sdata[t] = s;
    __syncthreads();
    for (int off = 1; off < 256; off <<= 1) {
        int v = (t >= off) ? sdata[t - off] : 0;
        __syncthreads();
        sdata[t] += v;
        __syncthreads();
    }
    int p = sdata[t] - s;
    if (base + 0 < N_NODES) { offsets[base + 0] = p; p += a0; }
    if (base + 1 < N_NODES) { offsets[base + 1] = p; p += a1; }
    if (base + 2 < N_NODES) { offsets[base + 2] = p; p += a2; }
    if (base + 3 < N_NODES) { offsets[base + 3] = p; }
    if (t == 255) part[blockIdx.x] = sdata[255];
}

// scanC: add scanned chunk prefix (computed in-wave), init cursor + sentinel
__global__ __launch_bounds__(256) void k_scanC(
    int* __restrict__ offsets, int* __restrict__ cursor,
    const int* __restrict__ part)
{
    __shared__ int s_add, s_tot;
    int t = threadIdx.x;
    if (t < 64) {
        int v   = (t < SCAN_NB) ? part[t] : 0;
        int pre = (t < (int)blockIdx.x) ? v : 0;
        for (int off = 1; off < 64; off <<= 1) {
            pre += __shfl_xor(pre, off);
            v   += __shfl_xor(v, off);
        }
        if (t == 0) { s_add = pre; s_tot = v; }
    }
    __syncthreads();
    int add = s_add;
    int base = blockIdx.x * SCAN_CHUNK + t * 4;
#pragma unroll
    for (int j = 0; j < 4; ++j) {
        int i = base + j;
        if (i < N_NODES) {
            int v = offsets[i] + add;
            offsets[i] = v;
            cursor[i]  = v;
        }
    }
    if (blockIdx.x == 0 && t == 0) offsets[N_NODES] = s_tot;
}

// ---------------------------------------------------------------------------
// Phase 2: bucket-grouped pairs -> final CSR. Cursor atomics hit a 2KB
// window, esrc scatter a 32KB window -> L2-resident, minimal HBM writes.
// ---------------------------------------------------------------------------
__global__ __launch_bounds__(256) void k_fill2(
    const uint2* __restrict__ epair, const int* __restrict__ bcur,
    int* __restrict__ cursor, int* __restrict__ esrc)
{
    int i = blockIdx.x * 256 + threadIdx.x;   // global slot
    int b = i / BCAP;
    if (b >= NBK) return;
    if (i < bcur[b]) {                        // bcur[b] = end of bucket b
        uint2 pd = epair[i];
        int pos = atomicAdd(&cursor[pd.y], 1);
        esrc[pos] = (int)pd.x;
    }
}

// ---------------------------------------------------------------------------
// Layer-1 pre-projection (MFMA): u1 = x@Wrel1, r1 = x@Wroot1+b1, bf16
// sigma-order rows (p=(lane&15)*4+ct -> true col ct*16+(lane&15)).
// ---------------------------------------------------------------------------
__global__ __launch_bounds__(256) void k_pre1(
    const float* __restrict__ x,
    const float* __restrict__ Wrel,    // [64][64] f32
    const float* __restrict__ Wroot,   // [64][64] f32
    const float* __restrict__ bias,    // [64] f32
    unsigned short* __restrict__ u1,
    unsigned short* __restrict__ r1)
{
    int lane = threadIdx.x & 63;
    int c15  = lane & 15;
    int q    = lane >> 4;

    bf16x8 bf[2][4][2];
#pragma unroll
    for (int mat = 0; mat < 2; ++mat) {
        const float* W = mat ? Wroot : Wrel;
#pragma unroll
        for (int ct = 0; ct < 4; ++ct) {
            int c = ct * 16 + c15;
#pragma unroll
            for (int kf = 0; kf < 2; ++kf) {
                int kb = kf * 32 + q * 8;
                bf16x8 f;
#pragma unroll
                for (int j = 0; j < 8; ++j)
                    f[j] = (short)f2b(W[(kb + j) * 64 + c]);
                bf[mat][ct][kf] = f;
            }
        }
    }
    float bv[4];
#pragma unroll
    for (int ct = 0; ct < 4; ++ct) bv[ct] = bias[ct * 16 + c15];

    int tile = (blockIdx.x * blockDim.x + threadIdx.x) >> 6;
    if (tile * 16 >= N_NODES) return;
    int row0 = tile * 16;

    const float* xr = x + (size_t)(row0 + c15) * 64;
    bf16x8 a0, a1;
#pragma unroll
    for (int j = 0; j < 8; ++j) {
        a0[j] = (short)f2b(xr[q * 8 + j]);
        a1[j] = (short)f2b(xr[32 + q * 8 + j]);
    }

    floatx4 z = {0.f, 0.f, 0.f, 0.f};
    floatx4 acc[2][4];
#pragma unroll
    for (int mat = 0; mat < 2; ++mat)
#pragma unroll
        for (int ct = 0; ct < 4; ++ct) {
            floatx4 a = __builtin_amdgcn_mfma_f32_16x16x32_bf16(a0, bf[mat][ct][0], z, 0, 0, 0);
            acc[mat][ct] = __builtin_amdgcn_mfma_f32_16x16x32_bf16(a1, bf[mat][ct][1], a, 0, 0, 0);
        }

#pragma unroll
    for (int reg = 0; reg < 4; ++reg) {
        int row = row0 + q * 4 + reg;
        uint2 uu, rr;
        uu.x = pk2(acc[0][0][reg],          acc[0][1][reg]);
        uu.y = pk2(acc[0][2][reg],          acc[0][3][reg]);
        rr.x = pk2(acc[1][0][reg] + bv[0],  acc[1][1][reg] + bv[1]);
        rr.y = pk2(acc[1][2][reg] + bv[2],  acc[1][3][reg] + bv[3]);
        *reinterpret_cast<uint2*>(u1 + (size_t)row * 64 + c15 * 4) = uu;
        *reinterpret_cast<uint2*>(r1 + (size_t)row * 64 + c15 * 4) = rr;
    }
}

// ---------------------------------------------------------------------------
// Aggregate layer 1 (sigma-order bf16): h = relu(sum u1[src] + r1)
// ---------------------------------------------------------------------------
__global__ __launch_bounds__(256) void k_agg64(
    const unsigned short* __restrict__ u1,
    const unsigned short* __restrict__ r1,
    const int* __restrict__ offsets, const int* __restrict__ esrc,
    unsigned short* __restrict__ h)
{
    int lane = threadIdx.x & 63;
    int node = (blockIdx.x * blockDim.x + threadIdx.x) >> 6;
    if (node >= N_NODES) return;
    int j    = lane & 15;
    int slot = lane >> 4;
    int beg = offsets[node], end = offsets[node + 1];
    float s0 = 0.f, s1 = 0.f, s2 = 0.f, s3 = 0.f;
    for (int e = beg + slot; e < end; e += 4) {
        int s = esrc[e];
        uint2 v = *reinterpret_cast<const uint2*>(u1 + (size_t)s * 64 + j * 4);
        s0 += blo(v.x); s1 += bhi(v.x);
        s2 += blo(v.y); s3 += bhi(v.y);
    }
    s0 += __shfl_xor(s0, 32); s1 += __shfl_xor(s1, 32);
    s2 += __shfl_xor(s2, 32); s3 += __shfl_xor(s3, 32);
    s0 += __shfl_xor(s0, 16); s1 += __shfl_xor(s1, 16);
    s2 += __shfl_xor(s2, 16); s3 += __shfl_xor(s3, 16);
    if (lane < 16) {
        uint2 rv = *reinterpret_cast<const uint2*>(r1 + (size_t)node * 64 + j * 4);
        float v0 = fmaxf(s0 + blo(rv.x), 0.f);
        float v1 = fmaxf(s1 + bhi(rv.x), 0.f);
        float v2 = fmaxf(s2 + blo(rv.y), 0.f);
        float v3 = fmaxf(s3 + bhi(rv.y), 0.f);
        uint2 o; o.x = pk2(v0, v1); o.y = pk2(v2, v3);
        *reinterpret_cast<uint2*>(h + (size_t)node * 64 + j * 4) = o;
    }
}

// ---------------------------------------------------------------------------
// Layer-2 pre-projection (MFMA), sigma-compensated weights; outputs
// sigma2-order [N][32] bf16.
// ---------------------------------------------------------------------------
__global__ __launch_bounds__(256) void k_pre2(
    const unsigned short* __restrict__ h,
    const float* __restrict__ Wrel,    // [64][32] f32
    const float* __restrict__ Wroot,   // [64][32] f32
    const float* __restrict__ bias,    // [32] f32
    unsigned short* __restrict__ u2,
    unsigned short* __restrict__ r2)
{
    int lane = threadIdx.x & 63;
    int c15  = lane & 15;
    int q    = lane >> 4;

    bf16x8 bf[2][2][2];
#pragma unroll
    for (int mat = 0; mat < 2; ++mat) {
        const float* W = mat ? Wroot : Wrel;
#pragma unroll
        for (int ct = 0; ct < 2; ++ct) {
            int c = ct * 16 + c15;
#pragma unroll
            for (int kf = 0; kf < 2; ++kf) {
                bf16x8 f;
#pragma unroll
                for (int j = 0; j < 8; ++j) {
                    int p = kf * 32 + q * 8 + j;
                    int tk = (p & 3) * 16 + (p >> 2);   // sigma(p)
                    f[j] = (short)f2b(W[tk * 32 + c]);
                }
                bf[mat][ct][kf] = f;
            }
        }
    }
    float bv[2];
#pragma unroll
    for (int ct = 0; ct < 2; ++ct) bv[ct] = bias[ct * 16 + c15];

    int tile = (blockIdx.x * blockDim.x + threadIdx.x) >> 6;
    if (tile * 16 >= N_NODES) return;
    int row0 = tile * 16;

    const unsigned short* hr = h + (size_t)(row0 + c15) * 64;
    bf16x8 a0 = *reinterpret_cast<const bf16x8*>(hr + q * 8);
    bf16x8 a1 = *reinterpret_cast<const bf16x8*>(hr + 32 + q * 8);

    floatx4 z = {0.f, 0.f, 0.f, 0.f};
    floatx4 acc[2][2];
#pragma unroll
    for (int mat = 0; mat < 2; ++mat)
#pragma unroll
        for (int ct = 0; ct < 2; ++ct) {
            floatx4 a = __builtin_amdgcn_mfma_f32_16x16x32_bf16(a0, bf[mat][ct][0], z, 0, 0, 0);
            acc[mat][ct] = __builtin_amdgcn_mfma_f32_16x16x32_bf16(a1, bf[mat][ct][1], a, 0, 0, 0);
        }

#pragma unroll
    for (int reg = 0; reg < 4; ++reg) {
        int row = row0 + q * 4 + reg;
        unsigned uu = pk2(acc[0][0][reg],         acc[0][1][reg]);
        unsigned rr = pk2(acc[1][0][reg] + bv[0], acc[1][1][reg] + bv[1]);
        *reinterpret_cast<unsigned*>(u2 + (size_t)row * 32 + c15 * 2) = uu;
        *reinterpret_cast<unsigned*>(r2 + (size_t)row * 32 + c15 * 2) = rr;
    }
}

// ---------------------------------------------------------------------------
// Aggregate layer 2 -> true row-major f32 out.
// ---------------------------------------------------------------------------
__global__ __launch_bounds__(256) void k_agg32(
    const unsigned short* __restrict__ u2,
    const unsigned short* __restrict__ r2,
    const int* __restrict__ offsets, const int* __restrict__ esrc,
    float* __restrict__ out)
{
    int lane = threadIdx.x & 63;
    int node = (blockIdx.x * blockDim.x + threadIdx.x) >> 6;
    if (node >= N_NODES) return;
    int j    = lane & 15;
    int slot = lane >> 4;
    int beg = offsets[node], end = offsets[node + 1];
    float s0 = 0.f, s1 = 0.f;
    for (int e = beg + slot; e < end; e += 4) {
        int s = esrc[e];
        unsigned v = *reinterpret_cast<const unsigned*>(u2 + (size_t)s * 32 + j * 2);
        s0 += blo(v); s1 += bhi(v);
    }
    s0 += __shfl_xor(s0, 32); s1 += __shfl_xor(s1, 32);
    s0 += __shfl_xor(s0, 16); s1 += __shfl_xor(s1, 16);
    if (lane < 16) {
        unsigned rv = *reinterpret_cast<const unsigned*>(r2 + (size_t)node * 32 + j * 2);
        out[(size_t)node * 32 + j]      = s0 + blo(rv);
        out[(size_t)node * 32 + 16 + j] = s1 + bhi(rv);
    }
}

extern "C" void kernel_launch(void* const* d_in, const int* in_sizes, int n_in,
                              void* d_out, int out_size, void* d_ws, size_t ws_size,
                              hipStream_t stream) {
    const float* x      = (const float*)d_in[0];
    const int*   ei     = (const int*)  d_in[1];
    const float* Wrel1  = (const float*)d_in[2];
    const float* Wroot1 = (const float*)d_in[3];
    const float* b1     = (const float*)d_in[4];
    const float* Wrel2  = (const float*)d_in[5];
    const float* Wroot2 = (const float*)d_in[6];
    const float* b2     = (const float*)d_in[7];
    float*       out    = (float*)d_out;

    const int* srcv = ei;
    const int* dstv = ei + N_EDGES;

    char* p = (char*)d_ws;
    auto alloc = [&](size_t bytes) {
        char* r = p;
        p += (bytes + 255) & ~(size_t)255;
        return r;
    };
    int*   counts  = (int*)  alloc(sizeof(int) * N_NODES);
    int*   offsets = (int*)  alloc(sizeof(int) * (N_NODES + 1));
    int*   cursor  = (int*)  alloc(sizeof(int) * N_NODES);
    int*   part    = (int*)  alloc(sizeof(int) * SCAN_NB);
    int*   bcur    = (int*)  alloc(sizeof(int) * NBK);
    uint2* epair   = (uint2*)alloc(sizeof(uint2) * (size_t)NBK * BCAP);
    int*   esrc    = (int*)  alloc(sizeof(int) * N_EDGES);
    unsigned short* u1 = (unsigned short*)alloc(sizeof(short) * (size_t)N_NODES * 64);
    unsigned short* r1 = (unsigned short*)alloc(sizeof(short) * (size_t)N_NODES * 64);
    unsigned short* h  = (unsigned short*)alloc(sizeof(short) * (size_t)N_NODES * 64);
    unsigned short* u2 = u1;   // reuse: u1/r1 dead after k_agg64
    unsigned short* r2 = r1;

    const int binBlocks  = (N_EDGES + BIN_TILE - 1) / BIN_TILE;          // 391
    const int fillBlocks = (NBK * BCAP + 255) / 256;                     // 3920
    const int nodeBlocks = (N_NODES * 64 + 255) / 256;                   // wave/node
    const int tileBlocks = ((N_NODES / 16) + 3) / 4;                     // wave/16-row tile

    // CSR build
    k_init <<<(N_NODES + 255) / 256, 256, 0, stream>>>(counts, bcur);
    k_bin  <<<binBlocks,  256, 0, stream>>>(srcv, dstv, counts, bcur, epair);
    k_scanA<<<SCAN_NB,    256, 0, stream>>>(counts, offsets, part);
    k_scanC<<<SCAN_NB,    256, 0, stream>>>(offsets, cursor, part);
    k_fill2<<<fillBlocks, 256, 0, stream>>>(epair, bcur, cursor, esrc);

    // Layer 1
    k_pre1 <<<tileBlocks, 256, 0, stream>>>(x, Wrel1, Wroot1, b1, u1, r1);
    k_agg64<<<nodeBlocks, 256, 0, stream>>>(u1, r1, offsets, esrc, h);

    // Layer 2
    k_pre2 <<<tileBlocks, 256, 0, stream>>>(h, Wrel2, Wroot2, b2, u2, r2);
    k_agg32<<<nodeBlocks, 256, 0, stream>>>(u2, r2, offsets, esrc, out);
}

// Round 6
// 111.691 us; speedup vs baseline: 4.9848x; 1.4029x over previous
//
#include <hip/hip_runtime.h>

static constexpr int N_NODES = 50000;
static constexpr int N_EDGES = 800000;

static constexpr int NBK      = 98;      // buckets of 512 dst-nodes (dst>>9)
static constexpr int BCAP     = 10240;   // slots/bucket (mean 8192, +22 sigma)
static constexpr int BIN_TILE = 2048;    // edges per k_bin block

typedef __attribute__((ext_vector_type(8))) short   bf16x8;
typedef __attribute__((ext_vector_type(4))) float   floatx4;

// f32 -> bf16 (RNE) as raw u16
__device__ __forceinline__ unsigned short f2b(float f) {
    union { float f; unsigned u; } v; v.f = f;
    unsigned r = v.u + 0x7FFFu + ((v.u >> 16) & 1u);
    return (unsigned short)(r >> 16);
}
__device__ __forceinline__ float blo(unsigned v) {
    union { unsigned u; float f; } c; c.u = v << 16; return c.f;
}
__device__ __forceinline__ float bhi(unsigned v) {
    union { unsigned u; float f; } c; c.u = v & 0xffff0000u; return c.f;
}
__device__ __forceinline__ unsigned pk2(float a, float b) {
    return (unsigned)f2b(a) | ((unsigned)f2b(b) << 16);
}

// ---------------------------------------------------------------------------
// Init bucket cursors (tiny, 1 block)
// ---------------------------------------------------------------------------
__global__ __launch_bounds__(128) void k_init(int* __restrict__ bcur)
{
    int i = threadIdx.x;
    if (i < NBK) bcur[i] = i * BCAP;
}

// ---------------------------------------------------------------------------
// Phase 1: bin (src,dst) pairs into 98 dst-buckets with COALESCED writes.
// NO per-node global atomics (cross-XCD line-bounce: 25MB writeback in R5).
// ---------------------------------------------------------------------------
__global__ __launch_bounds__(256) void k_bin(
    const int* __restrict__ srcv, const int* __restrict__ dstv,
    int* __restrict__ bcur, uint2* __restrict__ epair)
{
    __shared__ uint2 stage[BIN_TILE];      // 16 KB
    __shared__ int cnt[128];
    __shared__ int scn[128];
    __shared__ int pref[NBK];
    __shared__ int gbase[NBK];

    int tid   = threadIdx.x;
    int base  = blockIdx.x * BIN_TILE;
    int tileN = min(BIN_TILE, N_EDGES - base);

    if (tid < 128) cnt[tid] = 0;
    __syncthreads();

    int ss[8], dd[8], sl[8];
#pragma unroll
    for (int j = 0; j < 8; ++j) {
        int i = tid + j * 256;
        ss[j] = -1; dd[j] = 0; sl[j] = 0;
        if (i < tileN) {
            ss[j] = srcv[base + i];
            dd[j] = dstv[base + i];
            sl[j] = atomicAdd(&cnt[dd[j] >> 9], 1);   // LDS only
        }
    }
    __syncthreads();

    // exclusive scan of cnt[0..127]
    int own = (tid < 128) ? cnt[tid] : 0;
    if (tid < 128) scn[tid] = own;
    __syncthreads();
    for (int off = 1; off < 128; off <<= 1) {
        int t = 0;
        if (tid < 128 && tid >= off) t = scn[tid - off];
        __syncthreads();
        if (tid < 128) scn[tid] += t;
        __syncthreads();
    }
    if (tid < NBK) {
        pref[tid]  = scn[tid] - cnt[tid];
        gbase[tid] = atomicAdd(&bcur[tid], cnt[tid]);   // 98 atomics/block
    }
    __syncthreads();

#pragma unroll
    for (int j = 0; j < 8; ++j) {
        if (ss[j] >= 0) {
            int b = dd[j] >> 9;
            stage[pref[b] + sl[j]] = uint2{(unsigned)ss[j], (unsigned)dd[j]};
        }
    }
    __syncthreads();

    for (int i = tid; i < tileN; i += 256) {
        uint2 pd = stage[i];
        int b = (int)(pd.y >> 9);
        epair[(size_t)gbase[b] + (i - pref[b])] = pd;
    }
}

// ---------------------------------------------------------------------------
// Phase 2: one block per bucket. Histogram + scan + scatter all in LDS;
// zero node-indexed global atomics. Produces offsets[] and esrc[] directly.
// ---------------------------------------------------------------------------
__global__ __launch_bounds__(512) void k_build(
    const uint2* __restrict__ epair, const int* __restrict__ bcur,
    int* __restrict__ offsets, int* __restrict__ esrc)
{
    __shared__ int cnt[512];
    __shared__ int scn[512];
    __shared__ int cur[512];
    __shared__ int s_base;

    int b = blockIdx.x;
    int t = threadIdx.x;
    int node0 = b << 9;
    int ncnt  = min(512, N_NODES - node0);
    int beg   = b * BCAP;
    int m     = bcur[b] - beg;

    cnt[t] = 0;
    __syncthreads();

    for (int i = t; i < m; i += 512) {
        uint2 pd = epair[beg + i];
        atomicAdd(&cnt[(int)pd.y - node0], 1);
    }

    // bucket global base = sum of earlier buckets' sizes (lane t covers t, t+64)
    if (t < 64) {
        int m0 = (t      < NBK) ? (bcur[t]      - t * BCAP)        : 0;
        int m1 = (t + 64 < NBK) ? (bcur[t + 64] - (t + 64) * BCAP) : 0;
        int pre = ((t < b) ? m0 : 0) + ((t + 64 < b) ? m1 : 0);
        for (int off = 1; off < 64; off <<= 1) pre += __shfl_xor(pre, off);
        if (t == 0) s_base = pre;
    }
    __syncthreads();

    // exclusive scan of cnt[0..511]
    int own = cnt[t];
    scn[t] = own;
    __syncthreads();
    for (int off = 1; off < 512; off <<= 1) {
        int v = (t >= off) ? scn[t - off] : 0;
        __syncthreads();
        scn[t] += v;
        __syncthreads();
    }
    int start = s_base + scn[t] - own;
    cur[t] = start;
    if (t < ncnt) offsets[node0 + t] = start;
    if (b == 0 && t == 0) offsets[N_NODES] = N_EDGES;
    __syncthreads();

    // scatter src ids into this bucket's private ~33KB esrc window
    for (int i = t; i < m; i += 512) {
        uint2 pd = epair[beg + i];
        int sl = atomicAdd(&cur[(int)pd.y - node0], 1);
        esrc[sl] = (int)pd.x;
    }
}

// ---------------------------------------------------------------------------
// Layer-1 pre-projection (MFMA): u1 = x@Wrel1, r1 = x@Wroot1+b1, bf16
// sigma-order rows (p=(lane&15)*4+ct -> true col ct*16+(lane&15)).
// ---------------------------------------------------------------------------
__global__ __launch_bounds__(256) void k_pre1(
    const float* __restrict__ x,
    const float* __restrict__ Wrel,    // [64][64] f32
    const float* __restrict__ Wroot,   // [64][64] f32
    const float* __restrict__ bias,    // [64] f32
    unsigned short* __restrict__ u1,
    unsigned short* __restrict__ r1)
{
    int lane = threadIdx.x & 63;
    int c15  = lane & 15;
    int q    = lane >> 4;

    bf16x8 bf[2][4][2];
#pragma unroll
    for (int mat = 0; mat < 2; ++mat) {
        const float* W = mat ? Wroot : Wrel;
#pragma unroll
        for (int ct = 0; ct < 4; ++ct) {
            int c = ct * 16 + c15;
#pragma unroll
            for (int kf = 0; kf < 2; ++kf) {
                int kb = kf * 32 + q * 8;
                bf16x8 f;
#pragma unroll
                for (int j = 0; j < 8; ++j)
                    f[j] = (short)f2b(W[(kb + j) * 64 + c]);
                bf[mat][ct][kf] = f;
            }
        }
    }
    float bv[4];
#pragma unroll
    for (int ct = 0; ct < 4; ++ct) bv[ct] = bias[ct * 16 + c15];

    int tile = (blockIdx.x * blockDim.x + threadIdx.x) >> 6;
    if (tile * 16 >= N_NODES) return;
    int row0 = tile * 16;

    const float* xr = x + (size_t)(row0 + c15) * 64;
    bf16x8 a0, a1;
#pragma unroll
    for (int j = 0; j < 8; ++j) {
        a0[j] = (short)f2b(xr[q * 8 + j]);
        a1[j] = (short)f2b(xr[32 + q * 8 + j]);
    }

    floatx4 z = {0.f, 0.f, 0.f, 0.f};
    floatx4 acc[2][4];
#pragma unroll
    for (int mat = 0; mat < 2; ++mat)
#pragma unroll
        for (int ct = 0; ct < 4; ++ct) {
            floatx4 a = __builtin_amdgcn_mfma_f32_16x16x32_bf16(a0, bf[mat][ct][0], z, 0, 0, 0);
            acc[mat][ct] = __builtin_amdgcn_mfma_f32_16x16x32_bf16(a1, bf[mat][ct][1], a, 0, 0, 0);
        }

#pragma unroll
    for (int reg = 0; reg < 4; ++reg) {
        int row = row0 + q * 4 + reg;
        uint2 uu, rr;
        uu.x = pk2(acc[0][0][reg],          acc[0][1][reg]);
        uu.y = pk2(acc[0][2][reg],          acc[0][3][reg]);
        rr.x = pk2(acc[1][0][reg] + bv[0],  acc[1][1][reg] + bv[1]);
        rr.y = pk2(acc[1][2][reg] + bv[2],  acc[1][3][reg] + bv[3]);
        *reinterpret_cast<uint2*>(u1 + (size_t)row * 64 + c15 * 4) = uu;
        *reinterpret_cast<uint2*>(r1 + (size_t)row * 64 + c15 * 4) = rr;
    }
}

// ---------------------------------------------------------------------------
// Aggregate layer 1 (sigma-order bf16): h = relu(sum u1[src] + r1)
// ---------------------------------------------------------------------------
__global__ __launch_bounds__(256) void k_agg64(
    const unsigned short* __restrict__ u1,
    const unsigned short* __restrict__ r1,
    const int* __restrict__ offsets, const int* __restrict__ esrc,
    unsigned short* __restrict__ h)
{
    int lane = threadIdx.x & 63;
    int node = (blockIdx.x * blockDim.x + threadIdx.x) >> 6;
    if (node >= N_NODES) return;
    int j    = lane & 15;
    int slot = lane >> 4;
    int beg = offsets[node], end = offsets[node + 1];
    float s0 = 0.f, s1 = 0.f, s2 = 0.f, s3 = 0.f;
    for (int e = beg + slot; e < end; e += 4) {
        int s = esrc[e];
        uint2 v = *reinterpret_cast<const uint2*>(u1 + (size_t)s * 64 + j * 4);
        s0 += blo(v.x); s1 += bhi(v.x);
        s2 += blo(v.y); s3 += bhi(v.y);
    }
    s0 += __shfl_xor(s0, 32); s1 += __shfl_xor(s1, 32);
    s2 += __shfl_xor(s2, 32); s3 += __shfl_xor(s3, 32);
    s0 += __shfl_xor(s0, 16); s1 += __shfl_xor(s1, 16);
    s2 += __shfl_xor(s2, 16); s3 += __shfl_xor(s3, 16);
    if (lane < 16) {
        uint2 rv = *reinterpret_cast<const uint2*>(r1 + (size_t)node * 64 + j * 4);
        float v0 = fmaxf(s0 + blo(rv.x), 0.f);
        float v1 = fmaxf(s1 + bhi(rv.x), 0.f);
        float v2 = fmaxf(s2 + blo(rv.y), 0.f);
        float v3 = fmaxf(s3 + bhi(rv.y), 0.f);
        uint2 o; o.x = pk2(v0, v1); o.y = pk2(v2, v3);
        *reinterpret_cast<uint2*>(h + (size_t)node * 64 + j * 4) = o;
    }
}

// ---------------------------------------------------------------------------
// Layer-2 pre-projection (MFMA), sigma-compensated weights; outputs
// sigma2-order [N][32] bf16.
// ---------------------------------------------------------------------------
__global__ __launch_bounds__(256) void k_pre2(
    const unsigned short* __restrict__ h,
    const float* __restrict__ Wrel,    // [64][32] f32
    const float* __restrict__ Wroot,   // [64][32] f32
    const float* __restrict__ bias,    // [32] f32
    unsigned short* __restrict__ u2,
    unsigned short* __restrict__ r2)
{
    int lane = threadIdx.x & 63;
    int c15  = lane & 15;
    int q    = lane >> 4;

    bf16x8 bf[2][2][2];
#pragma unroll
    for (int mat = 0; mat < 2; ++mat) {
        const float* W = mat ? Wroot : Wrel;
#pragma unroll
        for (int ct = 0; ct < 2; ++ct) {
            int c = ct * 16 + c15;
#pragma unroll
            for (int kf = 0; kf < 2; ++kf) {
                bf16x8 f;
#pragma unroll
                for (int j = 0; j < 8; ++j) {
                    int p = kf * 32 + q * 8 + j;
                    int tk = (p & 3) * 16 + (p >> 2);   // sigma(p)
                    f[j] = (short)f2b(W[tk * 32 + c]);
                }
                bf[mat][ct][kf] = f;
            }
        }
    }
    float bv[2];
#pragma unroll
    for (int ct = 0; ct < 2; ++ct) bv[ct] = bias[ct * 16 + c15];

    int tile = (blockIdx.x * blockDim.x + threadIdx.x) >> 6;
    if (tile * 16 >= N_NODES) return;
    int row0 = tile * 16;

    const unsigned short* hr = h + (size_t)(row0 + c15) * 64;
    bf16x8 a0 = *reinterpret_cast<const bf16x8*>(hr + q * 8);
    bf16x8 a1 = *reinterpret_cast<const bf16x8*>(hr + 32 + q * 8);

    floatx4 z = {0.f, 0.f, 0.f, 0.f};
    floatx4 acc[2][2];
#pragma unroll
    for (int mat = 0; mat < 2; ++mat)
#pragma unroll
        for (int ct = 0; ct < 2; ++ct) {
            floatx4 a = __builtin_amdgcn_mfma_f32_16x16x32_bf16(a0, bf[mat][ct][0], z, 0, 0, 0);
            acc[mat][ct] = __builtin_amdgcn_mfma_f32_16x16x32_bf16(a1, bf[mat][ct][1], a, 0, 0, 0);
        }

#pragma unroll
    for (int reg = 0; reg < 4; ++reg) {
        int row = row0 + q * 4 + reg;
        unsigned uu = pk2(acc[0][0][reg],         acc[0][1][reg]);
        unsigned rr = pk2(acc[1][0][reg] + bv[0], acc[1][1][reg] + bv[1]);
        *reinterpret_cast<unsigned*>(u2 + (size_t)row * 32 + c15 * 2) = uu;
        *reinterpret_cast<unsigned*>(r2 + (size_t)row * 32 + c15 * 2) = rr;
    }
}

// ---------------------------------------------------------------------------
// Aggregate layer 2 -> true row-major f32 out.
// ---------------------------------------------------------------------------
__global__ __launch_bounds__(256) void k_agg32(
    const unsigned short* __restrict__ u2,
    const unsigned short* __restrict__ r2,
    const int* __restrict__ offsets, const int* __restrict__ esrc,
    float* __restrict__ out)
{
    int lane = threadIdx.x & 63;
    int node = (blockIdx.x * blockDim.x + threadIdx.x) >> 6;
    if (node >= N_NODES) return;
    int j    = lane & 15;
    int slot = lane >> 4;
    int beg = offsets[node], end = offsets[node + 1];
    float s0 = 0.f, s1 = 0.f;
    for (int e = beg + slot; e < end; e += 4) {
        int s = esrc[e];
        unsigned v = *reinterpret_cast<const unsigned*>(u2 + (size_t)s * 32 + j * 2);
        s0 += blo(v); s1 += bhi(v);
    }
    s0 += __shfl_xor(s0, 32); s1 += __shfl_xor(s1, 32);
    s0 += __shfl_xor(s0, 16); s1 += __shfl_xor(s1, 16);
    if (lane < 16) {
        unsigned rv = *reinterpret_cast<const unsigned*>(r2 + (size_t)node * 32 + j * 2);
        out[(size_t)node * 32 + j]      = s0 + blo(rv);
        out[(size_t)node * 32 + 16 + j] = s1 + bhi(rv);
    }
}

extern "C" void kernel_launch(void* const* d_in, const int* in_sizes, int n_in,
                              void* d_out, int out_size, void* d_ws, size_t ws_size,
                              hipStream_t stream) {
    const float* x      = (const float*)d_in[0];
    const int*   ei     = (const int*)  d_in[1];
    const float* Wrel1  = (const float*)d_in[2];
    const float* Wroot1 = (const float*)d_in[3];
    const float* b1     = (const float*)d_in[4];
    const float* Wrel2  = (const float*)d_in[5];
    const float* Wroot2 = (const float*)d_in[6];
    const float* b2     = (const float*)d_in[7];
    float*       out    = (float*)d_out;

    const int* srcv = ei;
    const int* dstv = ei + N_EDGES;

    char* p = (char*)d_ws;
    auto alloc = [&](size_t bytes) {
        char* r = p;
        p += (bytes + 255) & ~(size_t)255;
        return r;
    };
    int*   offsets = (int*)  alloc(sizeof(int) * (N_NODES + 1));
    int*   bcur    = (int*)  alloc(sizeof(int) * NBK);
    uint2* epair   = (uint2*)alloc(sizeof(uint2) * (size_t)NBK * BCAP);
    int*   esrc    = (int*)  alloc(sizeof(int) * N_EDGES);
    unsigned short* u1 = (unsigned short*)alloc(sizeof(short) * (size_t)N_NODES * 64);
    unsigned short* r1 = (unsigned short*)alloc(sizeof(short) * (size_t)N_NODES * 64);
    unsigned short* h  = (unsigned short*)alloc(sizeof(short) * (size_t)N_NODES * 64);
    unsigned short* u2 = u1;   // reuse: u1/r1 dead after k_agg64
    unsigned short* r2 = r1;

    const int binBlocks  = (N_EDGES + BIN_TILE - 1) / BIN_TILE;   // 391
    const int nodeBlocks = (N_NODES * 64 + 255) / 256;            // wave/node
    const int tileBlocks = ((N_NODES / 16) + 3) / 4;              // wave/16-row tile

    // CSR build (no node-indexed global atomics anywhere)
    k_init <<<1,         128, 0, stream>>>(bcur);
    k_bin  <<<binBlocks, 256, 0, stream>>>(srcv, dstv, bcur, epair);
    k_build<<<NBK,       512, 0, stream>>>(epair, bcur, offsets, esrc);

    // Layer 1
    k_pre1 <<<tileBlocks, 256, 0, stream>>>(x, Wrel1, Wroot1, b1, u1, r1);
    k_agg64<<<nodeBlocks, 256, 0, stream>>>(u1, r1, offsets, esrc, h);

    // Layer 2
    k_pre2 <<<tileBlocks, 256, 0, stream>>>(h, Wrel2, Wroot2, b2, u2, r2);
    k_agg32<<<nodeBlocks, 256, 0, stream>>>(u2, r2, offsets, esrc, out);
}